// Round 5
// baseline (203.593 us; speedup 1.0000x reference)
//
#include <hip/hip_runtime.h>
#include <hip/hip_bf16.h>
#include <math.h>

#define DM    1024
#define SEQL  2048
#define NB    2
#define MTOT  4096   // NB*SEQL

typedef __attribute__((ext_vector_type(8))) short short8;
typedef __attribute__((ext_vector_type(4))) short short4v;
typedef __attribute__((ext_vector_type(4))) float float4v;

// async global->LDS, 16B per lane; LDS dest is wave-uniform base (+ lane*16 implicit)
#define GLDS16(g, l) __builtin_amdgcn_global_load_lds( \
    (const __attribute__((address_space(1))) void*)(g), \
    (__attribute__((address_space(3))) void*)(l), 16, 0, 0)

__device__ __forceinline__ short f2bf(float f) {
  union { float f; unsigned u; } c; c.f = f;
  unsigned r = c.u + 0x7FFFu + ((c.u >> 16) & 1u);  // RNE
  return (short)(r >> 16);
}

// pack two fp32 -> dword of two bf16 (lo=a, hi=b); round-half-up (cheap, P>=0)
__device__ __forceinline__ int packbf(float a, float b) {
  union { float f; unsigned u; } ca, cb; ca.f = a; cb.f = b;
  return (int)__builtin_amdgcn_perm(cb.u + 0x8000u, ca.u + 0x8000u, 0x07060302u);
}

// One launch converting x + 4 weights fp32->bf16.
__global__ __launch_bounds__(256) void cvt_all(
    const float* __restrict__ x, const float* __restrict__ wq, const float* __restrict__ wk,
    const float* __restrict__ wv, const float* __restrict__ wo,
    short* __restrict__ xb, short* __restrict__ wqb, short* __restrict__ wkb,
    short* __restrict__ wvb, short* __restrict__ wob) {
  const int n4x = MTOT * DM / 4;        // 1,048,576
  int i = blockIdx.x * 256 + threadIdx.x;
  const float* s; short* d; int off;
  if (i < n4x) { s = x; d = xb; off = i; }
  else {
    int j = i - n4x;
    int sel = j >> 18;                  // DM*DM/4 = 262144 = 2^18
    off = j & 0x3FFFF;
    s = (sel == 0) ? wq : (sel == 1) ? wk : (sel == 2) ? wv : wo;
    d = (sel == 0) ? wqb : (sel == 1) ? wkb : (sel == 2) ? wvb : wob;
  }
  float4 v = ((const float4*)s)[off];
  short4v o;
  o.x = f2bf(v.x); o.y = f2bf(v.y); o.z = f2bf(v.z); o.w = f2bf(v.w);
  ((short4v*)d)[off] = o;
}

// Fused QKV projection, BK=64 (16 K-iters, half the barrier drains of BK=32).
// blockIdx.z picks Wq/Wk/Wv; z<2 -> RoPE bf16 store (z==0 folds 0.125*log2e
// attention scale into Q), z==2 -> transposed Vt store. LDS 32KB -> 3 blocks/CU.
__global__ __launch_bounds__(256, 3) void qkv_kernel(
    const short* __restrict__ A,
    const short* __restrict__ B0, const short* __restrict__ B1, const short* __restrict__ B2,
    short* __restrict__ out0, short* __restrict__ out1, short* __restrict__ out2,
    const float* __restrict__ cosp, const float* __restrict__ sinp)
{
  __shared__ short As[128 * 64];
  __shared__ short Bs[128 * 64];
  const int t = threadIdx.x;
  const int w = t >> 6, lane = t & 63;
  const int quad = lane >> 4, l16 = lane & 15;
  const int wm = w >> 1, wn = w & 1;
  const int bm = blockIdx.y * 128, bn = blockIdx.x * 128;

  const short* Bw = (blockIdx.z == 0) ? B0 : ((blockIdx.z == 1) ? B1 : B2);

  float4v acc[4][4];
#pragma unroll
  for (int i = 0; i < 4; ++i)
#pragma unroll
    for (int j = 0; j < 4; ++j) { float4v z = {0.f, 0.f, 0.f, 0.f}; acc[i][j] = z; }

  for (int k0 = 0; k0 < DM; k0 += 64) {
    // stage 128x64 A-tile and B-tile: 8 chunks/row, 4 chunks per thread each
#pragma unroll
    for (int j = 0; j < 4; ++j) {
      const int i = j * 256 + t;
      const int row = i >> 3, c = i & 7;
      GLDS16(A  + (size_t)(bm + row) * DM + k0 + c * 8, As + (j * 256 + w * 64) * 8);
      GLDS16(Bw + (size_t)(bn + row) * DM + k0 + c * 8, Bs + (j * 256 + w * 64) * 8);
    }
    __syncthreads();
#pragma unroll
    for (int kk2 = 0; kk2 < 2; ++kk2) {
      short8 af[4], bf[4];
#pragma unroll
      for (int mt = 0; mt < 4; ++mt)
        af[mt] = *(const short8*)&As[(wm * 64 + mt * 16 + l16) * 64 + kk2 * 32 + quad * 8];
#pragma unroll
      for (int nt = 0; nt < 4; ++nt)
        bf[nt] = *(const short8*)&Bs[(wn * 64 + nt * 16 + l16) * 64 + kk2 * 32 + quad * 8];
#pragma unroll
      for (int mt = 0; mt < 4; ++mt)
#pragma unroll
        for (int nt = 0; nt < 4; ++nt)
          acc[mt][nt] = __builtin_amdgcn_mfma_f32_16x16x32_bf16(af[mt], bf[nt], acc[mt][nt], 0, 0, 0);
    }
    __syncthreads();
  }

  if (blockIdx.z < 2) {
    // RoPE + bf16 store. Wave col-span is 64 = one head; pair (d, d+32) = (nt, nt+2).
    short* qo = (blockIdx.z == 0) ? out0 : out1;
    const float sc = (blockIdx.z == 0) ? 0.18033688011112042f : 1.0f;  // 0.125*log2(e) for Q
#pragma unroll
    for (int mt = 0; mt < 4; ++mt)
#pragma unroll
      for (int r = 0; r < 4; ++r) {
        int grow = bm + wm * 64 + mt * 16 + quad * 4 + r;
        int s = grow & (SEQL - 1);
        int base = grow * DM + bn + wn * 64;
#pragma unroll
        for (int nt = 0; nt < 2; ++nt) {
          int d1 = nt * 16 + l16;  // 0..31
          float q1 = acc[mt][nt][r], q2 = acc[mt][nt + 2][r];
          float c1 = cosp[s * 64 + d1] * sc,      s1 = sinp[s * 64 + d1] * sc;
          float c2 = cosp[s * 64 + 32 + d1] * sc, s2 = sinp[s * 64 + 32 + d1] * sc;
          qo[base + d1]      = f2bf(q1 * c1 - q2 * s1);
          qo[base + 32 + d1] = f2bf(q2 * c2 + q1 * s2);
        }
      }
  } else {
    // V stored transposed: Vt[n][b*S+s], 4 consecutive columns per lane -> 8B stores
    short* vo = out2;
#pragma unroll
    for (int mt = 0; mt < 4; ++mt)
#pragma unroll
      for (int nt = 0; nt < 4; ++nt) {
        int gc = bn + wn * 64 + nt * 16 + l16;
        int g0 = bm + wm * 64 + mt * 16 + quad * 4;
        short4v pk;
#pragma unroll
        for (int r = 0; r < 4; ++r) pk[r] = f2bf(acc[mt][nt][r]);
        *(short4v*)&vo[(size_t)gc * MTOT + g0] = pk;
      }
  }
}

#if __has_builtin(__builtin_amdgcn_mfma_f32_16x16x16bf16_1k)
#define HAVE_MFMA16 1
#define MFMA16(a, b, c) __builtin_amdgcn_mfma_f32_16x16x16bf16_1k(a, b, c, 0, 0, 0)
#else
#define HAVE_MFMA16 0
#endif

// Flash attention v5: ONE 64-row q-tile per block, grid (32,32)=1024 blocks,
// heavy-first (qt descending), 4 blocks/CU (LDS exactly 32KB, VGPR<=128).
// S^T = mfma(K,Q) so P^T's C-layout feeds PV directly from registers (no P LDS
// round-trip, no per-iter cross-lane reductions; fixed m=0, scale+log2e folded
// into Q). O accumulated transposed; packed 8B stores at end.
__global__ __launch_bounds__(256, 4) void attn_kernel(
    const short* __restrict__ Q, const short* __restrict__ K,
    const short* __restrict__ Vt, short* __restrict__ O)
{
  __shared__ short Ks[128 * 64];       // 16 KB, chunk-swizzled
  __shared__ short Vs[64 * 128];       // 16 KB, chunk-swizzled
  const int t = threadIdx.x;
  const int w = t >> 6, lane = t & 63;
  const int quad = lane >> 4, l16 = lane & 15;
  const int qt = 31 - blockIdx.x;      // descending: heavy blocks dispatched first
  const int bh = blockIdx.y;
  const int b = bh >> 4, h = bh & 15;
  const int rowbase = b * SEQL;
  const int colbase = h * 64;
  const int nkt = (qt >> 1) + 1;       // 1..16 (128-row k-tiles, causal)
  const int q = qt * 64 + w * 16 + l16;     // this lane's q (seq-local)

  // Q fragment (lane=q, elems=d) — serves as MFMA B-operand for S^T = K·Q^T
  short8 aq[2];
#pragma unroll
  for (int kk = 0; kk < 2; ++kk)
    aq[kk] = *(const short8*)&Q[(size_t)(rowbase + q) * DM + colbase + kk * 32 + quad * 8];

  float4v od[4];                       // O^T: row d=quad*4+r (+dt*16), col q=l16
#pragma unroll
  for (int j = 0; j < 4; ++j) { float4v z = {0.f, 0.f, 0.f, 0.f}; od[j] = z; }
  float lsum = 0.f;                    // per-lane partial row-sum (column q=l16)

  for (int kt = 0; kt < nkt; ++kt) {
    const bool diag = (kt == nkt - 1);
    // --- stage K-tile (128 x 64) and V-tile (64 x 128), xor-swizzled chunks ---
    {
      const short* Kbase = K + (size_t)(rowbase + kt * 128) * DM + colbase;
      const short* Vbase = Vt + (size_t)colbase * MTOT + rowbase + kt * 128;
#pragma unroll
      for (int j = 0; j < 4; ++j) {
        int i = j * 256 + t;                       // this lane's chunk id
        int n = i >> 3, c = (i & 7) ^ (n & 7);     // K: row n, global chunk c
        GLDS16(Kbase + (size_t)n * DM + c * 8, Ks + (j * 256 + w * 64) * 8);
      }
#pragma unroll
      for (int j = 0; j < 4; ++j) {
        int i = j * 256 + t;
        int d = i >> 4, c = (i & 15) ^ (d & 7);    // V: row d, global chunk c
        GLDS16(Vbase + (size_t)d * MTOT + c * 8, Vs + (j * 256 + w * 64) * 8);
      }
    }
    __syncthreads();

    // --- S^T = K Q^T per 16-row k-subtile; exp2; pack P^T to bf16 dwords ---
    int pk[8][2];                      // [subtile][dw]: dw0 = k quad*4+{0,1}, dw1 = +{2,3}
#pragma unroll
    for (int nt = 0; nt < 8; ++nt) {
      int n = nt * 16 + l16;
      short8 bk0 = *(const short8*)&Ks[(n * 8 + (quad ^ (n & 7))) * 8];
      short8 bk1 = *(const short8*)&Ks[(n * 8 + ((4 + quad) ^ (n & 7))) * 8];
      const int kb = kt * 128 + nt * 16 + quad * 4;     // this lane's k rows
      float4v zz = {0.f, 0.f, 0.f, 0.f};
      float4v s = __builtin_amdgcn_mfma_f32_16x16x32_bf16(bk0, aq[0], zz, 0, 0, 0);
      s = __builtin_amdgcn_mfma_f32_16x16x32_bf16(bk1, aq[1], s, 0, 0, 0);
      float pr[4];
#pragma unroll
      for (int r = 0; r < 4; ++r) {
        float p = (diag && (kb + r > q)) ? 0.f : __builtin_amdgcn_exp2f(s[r]);
        lsum += p; pr[r] = p;
      }
      pk[nt][0] = packbf(pr[0], pr[1]);
      pk[nt][1] = packbf(pr[2], pr[3]);
    }

    // --- O^T += V^T P^T ; V^T A-frags from LDS, P^T B-frags = pk (own lane!) ---
#if HAVE_MFMA16
#pragma unroll
    for (int kk = 0; kk < 8; ++kk) {   // 16-wide k chunks
      union { int i[2]; short4v s; } ub;
      ub.i[0] = pk[kk][0]; ub.i[1] = pk[kk][1];
#pragma unroll
      for (int dt = 0; dt < 4; ++dt) {
        int d = dt * 16 + l16;
        short4v av = *(const short4v*)&Vs[(d * 16 + ((kk * 2 + (quad >> 1)) ^ (d & 7))) * 8 + (quad & 1) * 4];
        od[dt] = MFMA16(av, ub.s, od[dt]);
      }
    }
#else
    // fallback: 16x16x32 PV with cross-quad shuffle assembly of B-frags
#pragma unroll
    for (int kk = 0; kk < 4; ++kk) {
      union { int i[4]; short8 s; } ub;
#pragma unroll
      for (int dj = 0; dj < 4; ++dj) {
        int src = (((quad & 1) * 2 + (dj >> 1)) << 4) + l16;
        int b0 = __shfl(pk[2 * kk][dj & 1], src);
        int b1 = __shfl(pk[2 * kk + 1][dj & 1], src);
        ub.i[dj] = (quad >= 2) ? b1 : b0;
      }
#pragma unroll
      for (int dt = 0; dt < 4; ++dt) {
        int d = dt * 16 + l16;
        short8 av = *(const short8*)&Vs[(d * 16 + ((kk * 4 + quad) ^ (d & 7))) * 8];
        od[dt] = __builtin_amdgcn_mfma_f32_16x16x32_bf16(av, ub.s, od[dt], 0, 0, 0);
      }
    }
#endif
    __syncthreads();
  }

  // --- reduce row-sum across the 4 quads sharing column q=l16 ---
  lsum += __shfl_xor(lsum, 16);
  lsum += __shfl_xor(lsum, 32);
  const float inv = 1.f / lsum;

  // --- store O (un-transposed on the fly): lane's q fixed, 4 consecutive d per dt ---
#pragma unroll
  for (int dt = 0; dt < 4; ++dt) {
    short4v sv;
#pragma unroll
    for (int r = 0; r < 4; ++r) sv[r] = f2bf(od[dt][r] * inv);
    int col = colbase + dt * 16 + quad * 4;
    *(short4v*)&O[(size_t)(rowbase + q) * DM + col] = sv;
  }
}

// Output projection: out = attn x Wo^T, 128m x 64n tiles (512 blocks), fp32 store.
__global__ __launch_bounds__(256, 2) void gemm_out(
    const short* __restrict__ A, const short* __restrict__ B,
    float* __restrict__ out)
{
  __shared__ short As[128 * 32];
  __shared__ short Bs[64 * 32];
  const int t = threadIdx.x;
  const int w = t >> 6, lane = t & 63;
  const int quad = lane >> 4, l16 = lane & 15;
  const int wm = w >> 1, wn = w & 1;
  const int bm = blockIdx.y * 128, bn = blockIdx.x * 64;

  float4v acc[4][2];
#pragma unroll
  for (int i = 0; i < 4; ++i)
#pragma unroll
    for (int j = 0; j < 2; ++j) { float4v z = {0.f, 0.f, 0.f, 0.f}; acc[i][j] = z; }

  for (int k0 = 0; k0 < DM; k0 += 32) {
#pragma unroll
    for (int i = 0; i < 2; ++i) {
      const int c = i * 256 + t;
      const int row = c >> 2, kc = c & 3;
      GLDS16(A + (size_t)(bm + row) * DM + k0 + kc * 8, As + (i * 256 + w * 64) * 8);
    }
    {
      const int row = t >> 2, kc = t & 3;
      GLDS16(B + (size_t)(bn + row) * DM + k0 + kc * 8, Bs + (w * 64) * 8);
    }
    __syncthreads();
    short8 af[4], bf[2];
#pragma unroll
    for (int mt = 0; mt < 4; ++mt) af[mt] = *(const short8*)&As[(wm * 64 + mt * 16 + l16) * 32 + quad * 8];
#pragma unroll
    for (int nt = 0; nt < 2; ++nt) bf[nt] = *(const short8*)&Bs[(wn * 32 + nt * 16 + l16) * 32 + quad * 8];
#pragma unroll
    for (int mt = 0; mt < 4; ++mt)
#pragma unroll
      for (int nt = 0; nt < 2; ++nt)
        acc[mt][nt] = __builtin_amdgcn_mfma_f32_16x16x32_bf16(af[mt], bf[nt], acc[mt][nt], 0, 0, 0);
    __syncthreads();
  }

#pragma unroll
  for (int mt = 0; mt < 4; ++mt)
#pragma unroll
    for (int nt = 0; nt < 2; ++nt)
#pragma unroll
      for (int r = 0; r < 4; ++r) {
        int grow = bm + wm * 64 + mt * 16 + quad * 4 + r;
        int gcol = bn + wn * 32 + nt * 16 + l16;
        out[(size_t)grow * DM + gcol] = acc[mt][nt][r];
      }
}

extern "C" void kernel_launch(void* const* d_in, const int* in_sizes, int n_in,
                              void* d_out, int out_size, void* d_ws, size_t ws_size,
                              hipStream_t stream) {
  const float* x    = (const float*)d_in[0];
  const float* cosp = (const float*)d_in[1];
  const float* sinp = (const float*)d_in[2];
  const float* Wq   = (const float*)d_in[3];
  const float* Wk   = (const float*)d_in[4];
  const float* Wv   = (const float*)d_in[5];
  const float* Wo   = (const float*)d_in[6];

  char* ws = (char*)d_ws;
  const size_t XB = (size_t)MTOT * DM * 2;  // 8 MB
  const size_t WB = (size_t)DM * DM * 2;    // 2 MB
  short* xb    = (short*)(ws);
  short* wqb   = (short*)(ws + XB);
  short* wkb   = (short*)(ws + XB + 1 * WB);
  short* wvb   = (short*)(ws + XB + 2 * WB);
  short* wob   = (short*)(ws + XB + 3 * WB);
  short* Qb    = (short*)(ws + XB + 4 * WB);
  short* Kb    = (short*)(ws + XB + 4 * WB + XB);
  short* Vtb   = (short*)(ws + XB + 4 * WB + 2 * XB);
  short* attnb = xb;  // x dead after QKV GEMMs; reuse its slot (total ws use: 40 MB)

  const int n4tot = (MTOT * DM + 4 * DM * DM) / 4;  // 2,097,152
  hipLaunchKernelGGL(cvt_all, dim3(n4tot / 256), dim3(256), 0, stream,
                     x, Wq, Wk, Wv, Wo, xb, wqb, wkb, wvb, wob);

  hipLaunchKernelGGL(qkv_kernel, dim3(DM / 128, MTOT / 128, 3), dim3(256), 0, stream,
                     xb, wqb, wkb, wvb, Qb, Kb, Vtb, cosp, sinp);

  hipLaunchKernelGGL(attn_kernel, dim3(32, NB * 16), dim3(256), 0, stream,
                     Qb, Kb, Vtb, attnb);

  hipLaunchKernelGGL(gemm_out, dim3(DM / 64, MTOT / 128), dim3(256), 0, stream,
                     attnb, wob, (float*)d_out);
}

// Round 6
// 201.260 us; speedup vs baseline: 1.0116x; 1.0116x over previous
//
#include <hip/hip_runtime.h>
#include <hip/hip_bf16.h>
#include <math.h>

#define DM    1024
#define SEQL  2048
#define NB    2
#define MTOT  4096   // NB*SEQL

typedef __attribute__((ext_vector_type(8))) short short8;
typedef __attribute__((ext_vector_type(4))) short short4v;
typedef __attribute__((ext_vector_type(4))) float float4v;

// async global->LDS, 16B per lane; LDS dest is wave-uniform base (+ lane*16 implicit)
#define GLDS16(g, l) __builtin_amdgcn_global_load_lds( \
    (const __attribute__((address_space(1))) void*)(g), \
    (__attribute__((address_space(3))) void*)(l), 16, 0, 0)

__device__ __forceinline__ short f2bf(float f) {
  union { float f; unsigned u; } c; c.f = f;
  unsigned r = c.u + 0x7FFFu + ((c.u >> 16) & 1u);  // RNE
  return (short)(r >> 16);
}

// pack two fp32 -> dword of two bf16 (lo=a, hi=b); round-half-up (cheap, P>=0)
__device__ __forceinline__ int packbf(float a, float b) {
  union { float f; unsigned u; } ca, cb; ca.f = a; cb.f = b;
  return (int)__builtin_amdgcn_perm(cb.u + 0x8000u, ca.u + 0x8000u, 0x07060302u);
}

// One launch converting x + 4 weights fp32->bf16.
__global__ __launch_bounds__(256) void cvt_all(
    const float* __restrict__ x, const float* __restrict__ wq, const float* __restrict__ wk,
    const float* __restrict__ wv, const float* __restrict__ wo,
    short* __restrict__ xb, short* __restrict__ wqb, short* __restrict__ wkb,
    short* __restrict__ wvb, short* __restrict__ wob) {
  const int n4x = MTOT * DM / 4;        // 1,048,576
  int i = blockIdx.x * 256 + threadIdx.x;
  const float* s; short* d; int off;
  if (i < n4x) { s = x; d = xb; off = i; }
  else {
    int j = i - n4x;
    int sel = j >> 18;                  // DM*DM/4 = 262144 = 2^18
    off = j & 0x3FFFF;
    s = (sel == 0) ? wq : (sel == 1) ? wk : (sel == 2) ? wv : wo;
    d = (sel == 0) ? wqb : (sel == 1) ? wkb : (sel == 2) ? wvb : wob;
  }
  float4 v = ((const float4*)s)[off];
  short4v o;
  o.x = f2bf(v.x); o.y = f2bf(v.y); o.z = f2bf(v.z); o.w = f2bf(v.w);
  ((short4v*)d)[off] = o;
}

// Fused QKV projection, BK=32, ping-pong double-buffered staging (single barrier
// per iter; prefetch of tile k+1 issued after the barrier, so the vmcnt drain at
// the NEXT barrier lands after a full compute phase). LDS 32KB -> 3 blocks/CU.
// blockIdx.z picks Wq/Wk/Wv; z<2 -> RoPE bf16 store (z==0 folds 0.125*log2e
// attention scale into Q), z==2 -> transposed Vt store.
__global__ __launch_bounds__(256, 3) void qkv_kernel(
    const short* __restrict__ A,
    const short* __restrict__ B0, const short* __restrict__ B1, const short* __restrict__ B2,
    short* __restrict__ out0, short* __restrict__ out1, short* __restrict__ out2,
    const float* __restrict__ cosp, const float* __restrict__ sinp)
{
  __shared__ short As[2][128 * 32];
  __shared__ short Bs[2][128 * 32];
  const int t = threadIdx.x;
  const int w = t >> 6, lane = t & 63;
  const int quad = lane >> 4, l16 = lane & 15;
  const int wm = w >> 1, wn = w & 1;
  const int bm = blockIdx.y * 128, bn = blockIdx.x * 128;

  const short* Bw = (blockIdx.z == 0) ? B0 : ((blockIdx.z == 1) ? B1 : B2);

  float4v acc[4][4];
#pragma unroll
  for (int i = 0; i < 4; ++i)
#pragma unroll
    for (int j = 0; j < 4; ++j) { float4v z = {0.f, 0.f, 0.f, 0.f}; acc[i][j] = z; }

  const int srow = t >> 2, skc = t & 3;          // staging coords (2 chunks/thread/matrix)
  auto stage = [&](int k0, int p) {
#pragma unroll
    for (int i = 0; i < 2; ++i) {
      const int row = (i * 256 + t) >> 2, kc = (i * 256 + t) & 3;
      GLDS16(A  + (size_t)(bm + row) * DM + k0 + kc * 8, &As[p][(i * 256 + w * 64) * 8]);
      GLDS16(Bw + (size_t)(bn + row) * DM + k0 + kc * 8, &Bs[p][(i * 256 + w * 64) * 8]);
    }
  };
  (void)srow; (void)skc;

  stage(0, 0);
  for (int ki = 0; ki < 32; ++ki) {
    const int p = ki & 1;
    __syncthreads();                              // drains prefetch issued last iter
    if (ki < 31) stage((ki + 1) * 32, p ^ 1);     // async prefetch into other buffer
    short8 af[4], bf[4];
#pragma unroll
    for (int mt = 0; mt < 4; ++mt) af[mt] = *(const short8*)&As[p][(wm * 64 + mt * 16 + l16) * 32 + quad * 8];
#pragma unroll
    for (int nt = 0; nt < 4; ++nt) bf[nt] = *(const short8*)&Bs[p][(wn * 64 + nt * 16 + l16) * 32 + quad * 8];
#pragma unroll
    for (int mt = 0; mt < 4; ++mt)
#pragma unroll
      for (int nt = 0; nt < 4; ++nt)
        acc[mt][nt] = __builtin_amdgcn_mfma_f32_16x16x32_bf16(af[mt], bf[nt], acc[mt][nt], 0, 0, 0);
  }

  if (blockIdx.z < 2) {
    // RoPE + bf16 store. Wave col-span is 64 = one head; pair (d, d+32) = (nt, nt+2).
    short* qo = (blockIdx.z == 0) ? out0 : out1;
    const float sc = (blockIdx.z == 0) ? 0.18033688011112042f : 1.0f;  // 0.125*log2(e) for Q
#pragma unroll
    for (int mt = 0; mt < 4; ++mt)
#pragma unroll
      for (int r = 0; r < 4; ++r) {
        int grow = bm + wm * 64 + mt * 16 + quad * 4 + r;
        int s = grow & (SEQL - 1);
        int base = grow * DM + bn + wn * 64;
#pragma unroll
        for (int nt = 0; nt < 2; ++nt) {
          int d1 = nt * 16 + l16;  // 0..31
          float q1 = acc[mt][nt][r], q2 = acc[mt][nt + 2][r];
          float c1 = cosp[s * 64 + d1] * sc,      s1 = sinp[s * 64 + d1] * sc;
          float c2 = cosp[s * 64 + 32 + d1] * sc, s2 = sinp[s * 64 + 32 + d1] * sc;
          qo[base + d1]      = f2bf(q1 * c1 - q2 * s1);
          qo[base + 32 + d1] = f2bf(q2 * c2 + q1 * s2);
        }
      }
  } else {
    // V stored transposed: Vt[n][b*S+s], 4 consecutive columns per lane -> 8B stores
    short* vo = out2;
#pragma unroll
    for (int mt = 0; mt < 4; ++mt)
#pragma unroll
      for (int nt = 0; nt < 4; ++nt) {
        int gc = bn + wn * 64 + nt * 16 + l16;
        int g0 = bm + wm * 64 + mt * 16 + quad * 4;
        short4v pk;
#pragma unroll
        for (int r = 0; r < 4; ++r) pk[r] = f2bf(acc[mt][nt][r]);
        *(short4v*)&vo[(size_t)gc * MTOT + g0] = pk;
      }
  }
}

#if __has_builtin(__builtin_amdgcn_mfma_f32_16x16x16bf16_1k)
#define HAVE_MFMA16 1
#define MFMA16(a, b, c) __builtin_amdgcn_mfma_f32_16x16x16bf16_1k(a, b, c, 0, 0, 0)
#else
#define HAVE_MFMA16 0
#endif

// Flash attention v6: balanced q-tile pair (i, 31-i) per block -> exactly 17
// tile-computes per block regardless of CU placement; grid (16,32)=512 blocks
// = 2/CU uniform. K/V tiles ping-pong double-buffered (64KB LDS), single
// barrier per iter with post-barrier prefetch -> global latency off the
// critical path. K/V fragment reads shared between the two q-tiles. S^T =
// mfma(K,Q); P^T feeds PV from registers (fixed m=0, scale+log2e in Q).
__global__ __launch_bounds__(256, 2) void attn_kernel(
    const short* __restrict__ Q, const short* __restrict__ K,
    const short* __restrict__ Vt, short* __restrict__ O)
{
  __shared__ short Ks[2][128 * 64];    // 2 x 16 KB, chunk-swizzled
  __shared__ short Vs[2][64 * 128];    // 2 x 16 KB, chunk-swizzled
  const int t = threadIdx.x;
  const int w = t >> 6, lane = t & 63;
  const int quad = lane >> 4, l16 = lane & 15;
  const int qtA = blockIdx.x;          // 0..15
  const int qtB = 31 - blockIdx.x;     // 31..16
  const int bh = blockIdx.y;
  const int b = bh >> 4, h = bh & 15;
  const int rowbase = b * SEQL;
  const int colbase = h * 64;
  const int nktA = (qtA >> 1) + 1;     // 1..8
  const int nktB = (qtB >> 1) + 1;     // 16..9
  const int qA = qtA * 64 + w * 16 + l16;
  const int qB = qtB * 64 + w * 16 + l16;

  // Q fragments (lane=q, elems=d) — MFMA B-operand for S^T = K·Q^T; pre-scaled.
  short8 aqA[2], aqB[2];
#pragma unroll
  for (int kk = 0; kk < 2; ++kk) {
    aqA[kk] = *(const short8*)&Q[(size_t)(rowbase + qA) * DM + colbase + kk * 32 + quad * 8];
    aqB[kk] = *(const short8*)&Q[(size_t)(rowbase + qB) * DM + colbase + kk * 32 + quad * 8];
  }

  float4v odA[4], odB[4];              // O^T: row d=quad*4+r (+dt*16), col q=l16
#pragma unroll
  for (int j = 0; j < 4; ++j) { float4v z = {0.f, 0.f, 0.f, 0.f}; odA[j] = z; odB[j] = z; }
  float lA = 0.f, lB = 0.f;

  auto stage = [&](int kt, int p) {
    const short* Kbase = K + (size_t)(rowbase + kt * 128) * DM + colbase;
    const short* Vbase = Vt + (size_t)colbase * MTOT + rowbase + kt * 128;
    short* kd = &Ks[p][0];
    short* vd = &Vs[p][0];
#pragma unroll
    for (int j = 0; j < 4; ++j) {
      int i = j * 256 + t;
      int n = i >> 3, c = (i & 7) ^ (n & 7);     // K: row n, xor-swizzled chunk
      GLDS16(Kbase + (size_t)n * DM + c * 8, kd + (j * 256 + w * 64) * 8);
    }
#pragma unroll
    for (int j = 0; j < 4; ++j) {
      int i = j * 256 + t;
      int d = i >> 4, c = (i & 15) ^ (d & 7);    // V: row d, xor-swizzled chunk
      GLDS16(Vbase + (size_t)d * MTOT + c * 8, vd + (j * 256 + w * 64) * 8);
    }
  };

  stage(0, 0);
  for (int kt = 0; kt < nktB; ++kt) {
    const int p = kt & 1;
    __syncthreads();                              // drains last iter's prefetch
    if (kt + 1 < nktB) stage(kt + 1, p ^ 1);      // async prefetch, other buffer
    const short* ks = &Ks[p][0];
    const short* vs = &Vs[p][0];
    const bool actA = (kt < nktA);
    const bool diagA = (kt == nktA - 1), diagB = (kt == nktB - 1);

    // --- S^T = K Q^T per 16-row k-subtile; exp2; pack P^T to bf16 dwords ---
    int pkA[8][2], pkB[8][2];
#pragma unroll
    for (int nt = 0; nt < 8; ++nt) {
      int n = nt * 16 + l16;
      short8 bk0 = *(const short8*)&ks[(n * 8 + (quad ^ (n & 7))) * 8];
      short8 bk1 = *(const short8*)&ks[(n * 8 + ((4 + quad) ^ (n & 7))) * 8];
      const int kb = kt * 128 + nt * 16 + quad * 4;
      float4v zz = {0.f, 0.f, 0.f, 0.f};
      float4v sB = __builtin_amdgcn_mfma_f32_16x16x32_bf16(bk0, aqB[0], zz, 0, 0, 0);
      sB = __builtin_amdgcn_mfma_f32_16x16x32_bf16(bk1, aqB[1], sB, 0, 0, 0);
      float pb[4];
#pragma unroll
      for (int r = 0; r < 4; ++r) {
        float pv = (diagB && (kb + r > qB)) ? 0.f : __builtin_amdgcn_exp2f(sB[r]);
        lB += pv; pb[r] = pv;
      }
      pkB[nt][0] = packbf(pb[0], pb[1]);
      pkB[nt][1] = packbf(pb[2], pb[3]);
      if (actA) {
        float4v sA = __builtin_amdgcn_mfma_f32_16x16x32_bf16(bk0, aqA[0], zz, 0, 0, 0);
        sA = __builtin_amdgcn_mfma_f32_16x16x32_bf16(bk1, aqA[1], sA, 0, 0, 0);
        float pa[4];
#pragma unroll
        for (int r = 0; r < 4; ++r) {
          float pv = (diagA && (kb + r > qA)) ? 0.f : __builtin_amdgcn_exp2f(sA[r]);
          lA += pv; pa[r] = pv;
        }
        pkA[nt][0] = packbf(pa[0], pa[1]);
        pkA[nt][1] = packbf(pa[2], pa[3]);
      }
    }

    // --- O^T += V^T P^T ; V^T frags from LDS (shared), P^T frags in-lane ---
#if HAVE_MFMA16
#pragma unroll
    for (int kk = 0; kk < 8; ++kk) {
      union { int i[2]; short4v s; } ubB, ubA;
      ubB.i[0] = pkB[kk][0]; ubB.i[1] = pkB[kk][1];
      if (actA) { ubA.i[0] = pkA[kk][0]; ubA.i[1] = pkA[kk][1]; }
#pragma unroll
      for (int dt = 0; dt < 4; ++dt) {
        int d = dt * 16 + l16;
        short4v av = *(const short4v*)&vs[(d * 16 + ((kk * 2 + (quad >> 1)) ^ (d & 7))) * 8 + (quad & 1) * 4];
        odB[dt] = MFMA16(av, ubB.s, odB[dt]);
        if (actA) odA[dt] = MFMA16(av, ubA.s, odA[dt]);
      }
    }
#else
#pragma unroll
    for (int kk = 0; kk < 4; ++kk) {
      union { int i[4]; short8 s; } ubB, ubA;
#pragma unroll
      for (int dj = 0; dj < 4; ++dj) {
        int src = (((quad & 1) * 2 + (dj >> 1)) << 4) + l16;
        int b0 = __shfl(pkB[2 * kk][dj & 1], src);
        int b1 = __shfl(pkB[2 * kk + 1][dj & 1], src);
        ubB.i[dj] = (quad >= 2) ? b1 : b0;
        int a0 = __shfl(pkA[2 * kk][dj & 1], src);
        int a1 = __shfl(pkA[2 * kk + 1][dj & 1], src);
        ubA.i[dj] = (quad >= 2) ? a1 : a0;
      }
#pragma unroll
      for (int dt = 0; dt < 4; ++dt) {
        int d = dt * 16 + l16;
        short8 av = *(const short8*)&vs[(d * 16 + ((kk * 4 + quad) ^ (d & 7))) * 8];
        odB[dt] = __builtin_amdgcn_mfma_f32_16x16x32_bf16(av, ubB.s, odB[dt], 0, 0, 0);
        if (actA) odA[dt] = __builtin_amdgcn_mfma_f32_16x16x32_bf16(av, ubA.s, odA[dt], 0, 0, 0);
      }
    }
#endif
  }

  // --- reduce row-sums across the 4 quads sharing column q=l16 ---
  lA += __shfl_xor(lA, 16); lA += __shfl_xor(lA, 32);
  lB += __shfl_xor(lB, 16); lB += __shfl_xor(lB, 32);
  const float iA = 1.f / lA, iB = 1.f / lB;

  // --- store O (un-transposed on the fly): lane's q fixed, 4 consecutive d per dt ---
#pragma unroll
  for (int dt = 0; dt < 4; ++dt) {
    short4v sa, sb;
#pragma unroll
    for (int r = 0; r < 4; ++r) { sa[r] = f2bf(odA[dt][r] * iA); sb[r] = f2bf(odB[dt][r] * iB); }
    int col = colbase + dt * 16 + quad * 4;
    *(short4v*)&O[(size_t)(rowbase + qA) * DM + col] = sa;
    *(short4v*)&O[(size_t)(rowbase + qB) * DM + col] = sb;
  }
}

// Output projection: out = attn x Wo^T, 128m x 64n tiles (512 blocks), fp32 store.
// Ping-pong double-buffered staging, single barrier per iter.
__global__ __launch_bounds__(256, 2) void gemm_out(
    const short* __restrict__ A, const short* __restrict__ B,
    float* __restrict__ out)
{
  __shared__ short As[2][128 * 32];
  __shared__ short Bs[2][64 * 32];
  const int t = threadIdx.x;
  const int w = t >> 6, lane = t & 63;
  const int quad = lane >> 4, l16 = lane & 15;
  const int wm = w >> 1, wn = w & 1;
  const int bm = blockIdx.y * 128, bn = blockIdx.x * 64;

  float4v acc[4][2];
#pragma unroll
  for (int i = 0; i < 4; ++i)
#pragma unroll
    for (int j = 0; j < 2; ++j) { float4v z = {0.f, 0.f, 0.f, 0.f}; acc[i][j] = z; }

  auto stage = [&](int k0, int p) {
#pragma unroll
    for (int i = 0; i < 2; ++i) {
      const int row = (i * 256 + t) >> 2, kc = (i * 256 + t) & 3;
      GLDS16(A + (size_t)(bm + row) * DM + k0 + kc * 8, &As[p][(i * 256 + w * 64) * 8]);
    }
    {
      const int row = t >> 2, kc = t & 3;
      GLDS16(B + (size_t)(bn + row) * DM + k0 + kc * 8, &Bs[p][(w * 64) * 8]);
    }
  };

  stage(0, 0);
  for (int ki = 0; ki < 32; ++ki) {
    const int p = ki & 1;
    __syncthreads();
    if (ki < 31) stage((ki + 1) * 32, p ^ 1);
    short8 af[4], bf[2];
#pragma unroll
    for (int mt = 0; mt < 4; ++mt) af[mt] = *(const short8*)&As[p][(wm * 64 + mt * 16 + l16) * 32 + quad * 8];
#pragma unroll
    for (int nt = 0; nt < 2; ++nt) bf[nt] = *(const short8*)&Bs[p][(wn * 32 + nt * 16 + l16) * 32 + quad * 8];
#pragma unroll
    for (int mt = 0; mt < 4; ++mt)
#pragma unroll
      for (int nt = 0; nt < 2; ++nt)
        acc[mt][nt] = __builtin_amdgcn_mfma_f32_16x16x32_bf16(af[mt], bf[nt], acc[mt][nt], 0, 0, 0);
  }

#pragma unroll
  for (int mt = 0; mt < 4; ++mt)
#pragma unroll
    for (int nt = 0; nt < 2; ++nt)
#pragma unroll
      for (int r = 0; r < 4; ++r) {
        int grow = bm + wm * 64 + mt * 16 + quad * 4 + r;
        int gcol = bn + wn * 32 + nt * 16 + l16;
        out[(size_t)grow * DM + gcol] = acc[mt][nt][r];
      }
}

extern "C" void kernel_launch(void* const* d_in, const int* in_sizes, int n_in,
                              void* d_out, int out_size, void* d_ws, size_t ws_size,
                              hipStream_t stream) {
  const float* x    = (const float*)d_in[0];
  const float* cosp = (const float*)d_in[1];
  const float* sinp = (const float*)d_in[2];
  const float* Wq   = (const float*)d_in[3];
  const float* Wk   = (const float*)d_in[4];
  const float* Wv   = (const float*)d_in[5];
  const float* Wo   = (const float*)d_in[6];

  char* ws = (char*)d_ws;
  const size_t XB = (size_t)MTOT * DM * 2;  // 8 MB
  const size_t WB = (size_t)DM * DM * 2;    // 2 MB
  short* xb    = (short*)(ws);
  short* wqb   = (short*)(ws + XB);
  short* wkb   = (short*)(ws + XB + 1 * WB);
  short* wvb   = (short*)(ws + XB + 2 * WB);
  short* wob   = (short*)(ws + XB + 3 * WB);
  short* Qb    = (short*)(ws + XB + 4 * WB);
  short* Kb    = (short*)(ws + XB + 4 * WB + XB);
  short* Vtb   = (short*)(ws + XB + 4 * WB + 2 * XB);
  short* attnb = xb;  // x dead after QKV GEMMs; reuse its slot (total ws use: 40 MB)

  const int n4tot = (MTOT * DM + 4 * DM * DM) / 4;  // 2,097,152
  hipLaunchKernelGGL(cvt_all, dim3(n4tot / 256), dim3(256), 0, stream,
                     x, Wq, Wk, Wv, Wo, xb, wqb, wkb, wvb, wob);

  hipLaunchKernelGGL(qkv_kernel, dim3(DM / 128, MTOT / 128, 3), dim3(256), 0, stream,
                     xb, wqb, wkb, wvb, Qb, Kb, Vtb, cosp, sinp);

  hipLaunchKernelGGL(attn_kernel, dim3(16, NB * 16), dim3(256), 0, stream,
                     Qb, Kb, Vtb, attnb);

  hipLaunchKernelGGL(gemm_out, dim3(DM / 64, MTOT / 128), dim3(256), 0, stream,
                     attnb, wob, (float*)d_out);
}

// Round 8
// 180.653 us; speedup vs baseline: 1.1270x; 1.1141x over previous
//
#include <hip/hip_runtime.h>
#include <hip/hip_bf16.h>
#include <math.h>

#define DM    1024
#define SEQL  2048
#define NB    2
#define MTOT  4096   // NB*SEQL

typedef __attribute__((ext_vector_type(8))) short short8;
typedef __attribute__((ext_vector_type(4))) short short4v;
typedef __attribute__((ext_vector_type(4))) float float4v;

// async global->LDS, 16B per lane; LDS dest is wave-uniform base (+ lane*16 implicit)
#define GLDS16(g, l) __builtin_amdgcn_global_load_lds( \
    (const __attribute__((address_space(1))) void*)(g), \
    (__attribute__((address_space(3))) void*)(l), 16, 0, 0)

__device__ __forceinline__ short f2bf(float f) {
  union { float f; unsigned u; } c; c.f = f;
  unsigned r = c.u + 0x7FFFu + ((c.u >> 16) & 1u);  // RNE
  return (short)(r >> 16);
}

// pack two fp32 -> dword of two bf16 (lo=a, hi=b); round-half-up (cheap, P>=0)
__device__ __forceinline__ int packbf(float a, float b) {
  union { float f; unsigned u; } ca, cb; ca.f = a; cb.f = b;
  return (int)__builtin_amdgcn_perm(cb.u + 0x8000u, ca.u + 0x8000u, 0x07060302u);
}

// One launch converting x + 4 weights fp32->bf16.
__global__ __launch_bounds__(256) void cvt_all(
    const float* __restrict__ x, const float* __restrict__ wq, const float* __restrict__ wk,
    const float* __restrict__ wv, const float* __restrict__ wo,
    short* __restrict__ xb, short* __restrict__ wqb, short* __restrict__ wkb,
    short* __restrict__ wvb, short* __restrict__ wob) {
  const int n4x = MTOT * DM / 4;        // 1,048,576
  int i = blockIdx.x * 256 + threadIdx.x;
  const float* s; short* d; int off;
  if (i < n4x) { s = x; d = xb; off = i; }
  else {
    int j = i - n4x;
    int sel = j >> 18;                  // DM*DM/4 = 262144 = 2^18
    off = j & 0x3FFFF;
    s = (sel == 0) ? wq : (sel == 1) ? wk : (sel == 2) ? wv : wo;
    d = (sel == 0) ? wqb : (sel == 1) ? wkb : (sel == 2) ? wvb : wob;
  }
  float4 v = ((const float4*)s)[off];
  short4v o;
  o.x = f2bf(v.x); o.y = f2bf(v.y); o.z = f2bf(v.z); o.w = f2bf(v.w);
  ((short4v*)d)[off] = o;
}

// Fused QKV projection, BK=32, ping-pong double-buffered staging.
// blockIdx.z picks Wq/Wk/Wv; z<2 -> RoPE bf16 store (z==0 folds 0.125*log2e
// attention scale into Q), z==2 -> transposed Vt store.
__global__ __launch_bounds__(256, 3) void qkv_kernel(
    const short* __restrict__ A,
    const short* __restrict__ B0, const short* __restrict__ B1, const short* __restrict__ B2,
    short* __restrict__ out0, short* __restrict__ out1, short* __restrict__ out2,
    const float* __restrict__ cosp, const float* __restrict__ sinp)
{
  __shared__ short As[2][128 * 32];
  __shared__ short Bs[2][128 * 32];
  const int t = threadIdx.x;
  const int w = t >> 6, lane = t & 63;
  const int quad = lane >> 4, l16 = lane & 15;
  const int wm = w >> 1, wn = w & 1;
  const int bm = blockIdx.y * 128, bn = blockIdx.x * 128;

  const short* Bw = (blockIdx.z == 0) ? B0 : ((blockIdx.z == 1) ? B1 : B2);

  float4v acc[4][4];
#pragma unroll
  for (int i = 0; i < 4; ++i)
#pragma unroll
    for (int j = 0; j < 4; ++j) { float4v z = {0.f, 0.f, 0.f, 0.f}; acc[i][j] = z; }

  auto stage = [&](int k0, int p) {
#pragma unroll
    for (int i = 0; i < 2; ++i) {
      const int row = (i * 256 + t) >> 2, kc = (i * 256 + t) & 3;
      GLDS16(A  + (size_t)(bm + row) * DM + k0 + kc * 8, &As[p][(i * 256 + w * 64) * 8]);
      GLDS16(Bw + (size_t)(bn + row) * DM + k0 + kc * 8, &Bs[p][(i * 256 + w * 64) * 8]);
    }
  };

  stage(0, 0);
  for (int ki = 0; ki < 32; ++ki) {
    const int p = ki & 1;
    __syncthreads();
    if (ki < 31) stage((ki + 1) * 32, p ^ 1);
    short8 af[4], bf[4];
#pragma unroll
    for (int mt = 0; mt < 4; ++mt) af[mt] = *(const short8*)&As[p][(wm * 64 + mt * 16 + l16) * 32 + quad * 8];
#pragma unroll
    for (int nt = 0; nt < 4; ++nt) bf[nt] = *(const short8*)&Bs[p][(wn * 64 + nt * 16 + l16) * 32 + quad * 8];
#pragma unroll
    for (int mt = 0; mt < 4; ++mt)
#pragma unroll
      for (int nt = 0; nt < 4; ++nt)
        acc[mt][nt] = __builtin_amdgcn_mfma_f32_16x16x32_bf16(af[mt], bf[nt], acc[mt][nt], 0, 0, 0);
  }

  if (blockIdx.z < 2) {
    short* qo = (blockIdx.z == 0) ? out0 : out1;
    const float sc = (blockIdx.z == 0) ? 0.18033688011112042f : 1.0f;  // 0.125*log2(e) for Q
#pragma unroll
    for (int mt = 0; mt < 4; ++mt)
#pragma unroll
      for (int r = 0; r < 4; ++r) {
        int grow = bm + wm * 64 + mt * 16 + quad * 4 + r;
        int s = grow & (SEQL - 1);
        int base = grow * DM + bn + wn * 64;
#pragma unroll
        for (int nt = 0; nt < 2; ++nt) {
          int d1 = nt * 16 + l16;  // 0..31
          float q1 = acc[mt][nt][r], q2 = acc[mt][nt + 2][r];
          float c1 = cosp[s * 64 + d1] * sc,      s1 = sinp[s * 64 + d1] * sc;
          float c2 = cosp[s * 64 + 32 + d1] * sc, s2 = sinp[s * 64 + 32 + d1] * sc;
          qo[base + d1]      = f2bf(q1 * c1 - q2 * s1);
          qo[base + 32 + d1] = f2bf(q2 * c2 + q1 * s2);
        }
      }
  } else {
    short* vo = out2;
#pragma unroll
    for (int mt = 0; mt < 4; ++mt)
#pragma unroll
      for (int nt = 0; nt < 4; ++nt) {
        int gc = bn + wn * 64 + nt * 16 + l16;
        int g0 = bm + wm * 64 + mt * 16 + quad * 4;
        short4v pk;
#pragma unroll
        for (int r = 0; r < 4; ++r) pk[r] = f2bf(acc[mt][nt][r]);
        *(short4v*)&vo[(size_t)gc * MTOT + g0] = pk;
      }
  }
}

// Flash attention v7b: 512-thread blocks, pair (i,31-i) -> uniform 17 iters.
// 8 waves split the K-DIMENSION of each staged 128-k tile (g=0: k 0..63,
// g=1: k 64..127); fixed m=0 makes the k accumulation a plain sum, so groups
// hold independent O/lsum partials merged in the epilogue via LDS.
// S^T = mfma(K,Q): lane's lsum is for q=l16. PV = mfma(P,V): lane's O rows are
// q=quad*4+r -> normalizer transposed via __shfl in the epilogue (v7 bug fix).
__global__ __launch_bounds__(512, 4) void attn_kernel(
    const short* __restrict__ Q, const short* __restrict__ K,
    const short* __restrict__ Vt, short* __restrict__ O)
{
  __shared__ short smem[34816];        // 68 KB: Ks 16K | Vs 16K | P strips 36K
  short* Ks = smem;                    // [128 n][8 chunks], xor-swizzled
  short* Vs = smem + 8192;             // [64 d][16 chunks], xor-swizzled
  const int t = threadIdx.x;
  const int wid = t >> 6, lane = t & 63;
  const int quad = lane >> 4, l16 = lane & 15;
  const int g = wid >> 2;              // k-half group: 0 -> k 0..63, 1 -> 64..127
  const int qg = wid & 3;              // q-row group (16 rows)
  short* Pl = smem + 16384 + wid * (2 * 16 * 72);  // per-wave strips [2 tiles][16 q][72]
  const int qtA = blockIdx.x, qtB = 31 - blockIdx.x;
  const int bh = blockIdx.y, b = bh >> 4, h = bh & 15;
  const int rowbase = b * SEQL, colbase = h * 64;
  const int nktA = (qtA >> 1) + 1, nktB = (qtB >> 1) + 1;
  const int qA = qtA * 64 + qg * 16 + l16;
  const int qB = qtB * 64 + qg * 16 + l16;

  // Q fragments (lane=q, elems=d): MFMA B-operand for S^T = K·Q^T (pre-scaled)
  short8 aqA[2], aqB[2];
#pragma unroll
  for (int kk = 0; kk < 2; ++kk) {
    aqA[kk] = *(const short8*)&Q[(size_t)(rowbase + qA) * DM + colbase + kk * 32 + quad * 8];
    aqB[kk] = *(const short8*)&Q[(size_t)(rowbase + qB) * DM + colbase + kk * 32 + quad * 8];
  }

  float4v oA[4], oB[4];                // O: row q=quad*4+r, col d=dt*16+l16 (k-half partial)
#pragma unroll
  for (int j = 0; j < 4; ++j) { float4v z = {0.f, 0.f, 0.f, 0.f}; oA[j] = z; oB[j] = z; }
  float lA = 0.f, lB = 0.f;            // per-lane partial row-sum, indexed by q = l16

  for (int kt = 0; kt < nktB; ++kt) {
    // --- stage K-tile (128x64) and V-tile (64x128), xor-swizzled, 512 threads ---
    {
      const short* Kbase = K + (size_t)(rowbase + kt * 128) * DM + colbase;
      const short* Vbase = Vt + (size_t)colbase * MTOT + rowbase + kt * 128;
#pragma unroll
      for (int j = 0; j < 2; ++j) {
        int i = j * 512 + t;
        int n = i >> 3, c = (i & 7) ^ (n & 7);
        GLDS16(Kbase + (size_t)n * DM + c * 8, Ks + (j * 512 + wid * 64) * 8);
      }
#pragma unroll
      for (int j = 0; j < 2; ++j) {
        int i = j * 512 + t;
        int d = i >> 4, c = (i & 15) ^ (d & 7);
        GLDS16(Vbase + (size_t)d * MTOT + c * 8, Vs + (j * 512 + wid * 64) * 8);
      }
    }
    __syncthreads();
    const bool actA = (kt < nktA);
    const bool diagA = (kt == nktA - 1), diagB = (kt == nktB - 1);

    // --- S^T = K Q^T on this wave's 4 nt-subtiles; exp2; P^T -> strip (b64) ---
#pragma unroll
    for (int ntl = 0; ntl < 4; ++ntl) {
      const int nt = g * 4 + ntl;
      const int n = nt * 16 + l16;
      short8 bk0 = *(const short8*)&Ks[(n * 8 + (quad ^ (n & 7))) * 8];
      short8 bk1 = *(const short8*)&Ks[(n * 8 + ((4 + quad) ^ (n & 7))) * 8];
      const int kb = kt * 128 + nt * 16 + quad * 4;
      float4v zz = {0.f, 0.f, 0.f, 0.f};
      float4v sB = __builtin_amdgcn_mfma_f32_16x16x32_bf16(bk0, aqB[0], zz, 0, 0, 0);
      sB = __builtin_amdgcn_mfma_f32_16x16x32_bf16(bk1, aqB[1], sB, 0, 0, 0);
      float pb[4];
#pragma unroll
      for (int r = 0; r < 4; ++r) {
        float pv = (diagB && (kb + r > qB)) ? 0.f : __builtin_amdgcn_exp2f(sB[r]);
        lB += pv; pb[r] = pv;
      }
      *(int2*)&Pl[1 * 16 * 72 + l16 * 72 + ntl * 16 + quad * 4] =
          make_int2(packbf(pb[0], pb[1]), packbf(pb[2], pb[3]));
      if (actA) {
        float4v sA = __builtin_amdgcn_mfma_f32_16x16x32_bf16(bk0, aqA[0], zz, 0, 0, 0);
        sA = __builtin_amdgcn_mfma_f32_16x16x32_bf16(bk1, aqA[1], sA, 0, 0, 0);
        float pa[4];
#pragma unroll
        for (int r = 0; r < 4; ++r) {
          float pv = (diagA && (kb + r > qA)) ? 0.f : __builtin_amdgcn_exp2f(sA[r]);
          lA += pv; pa[r] = pv;
        }
        *(int2*)&Pl[0 * 16 * 72 + l16 * 72 + ntl * 16 + quad * 4] =
            make_int2(packbf(pa[0], pa[1]), packbf(pa[2], pa[3]));
      }
    }

    // --- O += P V over this wave's 64-k half; V frags shared between tiles ---
#pragma unroll
    for (int kk = 0; kk < 2; ++kk) {
      short8 apB = *(const short8*)&Pl[1 * 16 * 72 + l16 * 72 + kk * 32 + quad * 8];
      short8 apA;
      if (actA) apA = *(const short8*)&Pl[0 * 16 * 72 + l16 * 72 + kk * 32 + quad * 8];
      const int c0 = g * 8 + kk * 4 + quad;     // k-chunk index in Vs
#pragma unroll
      for (int dt = 0; dt < 4; ++dt) {
        const int d = dt * 16 + l16;
        short8 bv = *(const short8*)&Vs[(d * 16 + (c0 ^ (d & 7))) * 8];
        oB[dt] = __builtin_amdgcn_mfma_f32_16x16x32_bf16(apB, bv, oB[dt], 0, 0, 0);
        if (actA) oA[dt] = __builtin_amdgcn_mfma_f32_16x16x32_bf16(apA, bv, oA[dt], 0, 0, 0);
      }
    }
    __syncthreads();
  }

  // --- quad-reduce lsum within wave (sum over this wave's k-half); per q=l16 ---
  lA += __shfl_xor(lA, 16); lA += __shfl_xor(lA, 32);
  lB += __shfl_xor(lB, 16); lB += __shfl_xor(lB, 32);

  // --- merge the two k-half groups via LDS, then normalize + store (group 0) ---
  __syncthreads();
  float* Ored = (float*)smem;                   // [2 tiles][4 qg][16 q][66]
  float* Lred = (float*)smem + 8448;            // [2 tiles][4 qg][16 q]
  if (g == 1) {
#pragma unroll
    for (int tile = 0; tile < 2; ++tile) {
      const float4v* src = (tile == 0) ? oA : oB;
      const int base = ((tile * 4 + qg) * 16) * 66;
#pragma unroll
      for (int dt = 0; dt < 4; ++dt)
#pragma unroll
        for (int r = 0; r < 4; ++r)
          Ored[base + (quad * 4 + r) * 66 + dt * 16 + l16] = src[dt][r];
    }
    if (lane < 16) {
      Lred[(0 * 4 + qg) * 16 + l16] = lA;
      Lred[(1 * 4 + qg) * 16 + l16] = lB;
    }
  }
  __syncthreads();
  if (g == 0) {
    // totals are indexed by q = l16; O rows are q = quad*4+r -> transpose the
    // normalizer via lane shuffles (source lane s = quad*4+r has l16 == s).
    const float tA = lA + Lred[(0 * 4 + qg) * 16 + l16];
    const float tB = lB + Lred[(1 * 4 + qg) * 16 + l16];
    float iAr[4], iBr[4];
#pragma unroll
    for (int r = 0; r < 4; ++r) {
      iAr[r] = 1.f / __shfl(tA, quad * 4 + r);
      iBr[r] = 1.f / __shfl(tB, quad * 4 + r);
    }
#pragma unroll
    for (int tile = 0; tile < 2; ++tile) {
      const float4v* src = (tile == 0) ? oA : oB;
      const int qt = (tile == 0) ? qtA : qtB;
      const int base = ((tile * 4 + qg) * 16) * 66;
#pragma unroll
      for (int dt = 0; dt < 4; ++dt)
#pragma unroll
        for (int r = 0; r < 4; ++r) {
          float v = src[dt][r] + Ored[base + (quad * 4 + r) * 66 + dt * 16 + l16];
          int grow = rowbase + qt * 64 + qg * 16 + quad * 4 + r;
          int gcol = colbase + dt * 16 + l16;
          O[(size_t)grow * DM + gcol] = f2bf(v * ((tile == 0) ? iAr[r] : iBr[r]));
        }
    }
  }
}

// Output projection: out = attn x Wo^T, 128m x 64n tiles (512 blocks), fp32 store.
__global__ __launch_bounds__(256, 2) void gemm_out(
    const short* __restrict__ A, const short* __restrict__ B,
    float* __restrict__ out)
{
  __shared__ short As[2][128 * 32];
  __shared__ short Bs[2][64 * 32];
  const int t = threadIdx.x;
  const int w = t >> 6, lane = t & 63;
  const int quad = lane >> 4, l16 = lane & 15;
  const int wm = w >> 1, wn = w & 1;
  const int bm = blockIdx.y * 128, bn = blockIdx.x * 64;

  float4v acc[4][2];
#pragma unroll
  for (int i = 0; i < 4; ++i)
#pragma unroll
    for (int j = 0; j < 2; ++j) { float4v z = {0.f, 0.f, 0.f, 0.f}; acc[i][j] = z; }

  auto stage = [&](int k0, int p) {
#pragma unroll
    for (int i = 0; i < 2; ++i) {
      const int row = (i * 256 + t) >> 2, kc = (i * 256 + t) & 3;
      GLDS16(A + (size_t)(bm + row) * DM + k0 + kc * 8, &As[p][(i * 256 + w * 64) * 8]);
    }
    {
      const int row = t >> 2, kc = t & 3;
      GLDS16(B + (size_t)(bn + row) * DM + k0 + kc * 8, &Bs[p][(w * 64) * 8]);
    }
  };

  stage(0, 0);
  for (int ki = 0; ki < 32; ++ki) {
    const int p = ki & 1;
    __syncthreads();
    if (ki < 31) stage((ki + 1) * 32, p ^ 1);
    short8 af[4], bf[2];
#pragma unroll
    for (int mt = 0; mt < 4; ++mt) af[mt] = *(const short8*)&As[p][(wm * 64 + mt * 16 + l16) * 32 + quad * 8];
#pragma unroll
    for (int nt = 0; nt < 2; ++nt) bf[nt] = *(const short8*)&Bs[p][(wn * 32 + nt * 16 + l16) * 32 + quad * 8];
#pragma unroll
    for (int mt = 0; mt < 4; ++mt)
#pragma unroll
      for (int nt = 0; nt < 2; ++nt)
        acc[mt][nt] = __builtin_amdgcn_mfma_f32_16x16x32_bf16(af[mt], bf[nt], acc[mt][nt], 0, 0, 0);
  }

#pragma unroll
  for (int mt = 0; mt < 4; ++mt)
#pragma unroll
    for (int nt = 0; nt < 2; ++nt)
#pragma unroll
      for (int r = 0; r < 4; ++r) {
        int grow = bm + wm * 64 + mt * 16 + quad * 4 + r;
        int gcol = bn + wn * 32 + nt * 16 + l16;
        out[(size_t)grow * DM + gcol] = acc[mt][nt][r];
      }
}

extern "C" void kernel_launch(void* const* d_in, const int* in_sizes, int n_in,
                              void* d_out, int out_size, void* d_ws, size_t ws_size,
                              hipStream_t stream) {
  const float* x    = (const float*)d_in[0];
  const float* cosp = (const float*)d_in[1];
  const float* sinp = (const float*)d_in[2];
  const float* Wq   = (const float*)d_in[3];
  const float* Wk   = (const float*)d_in[4];
  const float* Wv   = (const float*)d_in[5];
  const float* Wo   = (const float*)d_in[6];

  char* ws = (char*)d_ws;
  const size_t XB = (size_t)MTOT * DM * 2;  // 8 MB
  const size_t WB = (size_t)DM * DM * 2;    // 2 MB
  short* xb    = (short*)(ws);
  short* wqb   = (short*)(ws + XB);
  short* wkb   = (short*)(ws + XB + 1 * WB);
  short* wvb   = (short*)(ws + XB + 2 * WB);
  short* wob   = (short*)(ws + XB + 3 * WB);
  short* Qb    = (short*)(ws + XB + 4 * WB);
  short* Kb    = (short*)(ws + XB + 4 * WB + XB);
  short* Vtb   = (short*)(ws + XB + 4 * WB + 2 * XB);
  short* attnb = xb;  // x dead after QKV GEMMs; reuse its slot

  const int n4tot = (MTOT * DM + 4 * DM * DM) / 4;  // 2,097,152
  hipLaunchKernelGGL(cvt_all, dim3(n4tot / 256), dim3(256), 0, stream,
                     x, Wq, Wk, Wv, Wo, xb, wqb, wkb, wvb, wob);

  hipLaunchKernelGGL(qkv_kernel, dim3(DM / 128, MTOT / 128, 3), dim3(256), 0, stream,
                     xb, wqb, wkb, wvb, Qb, Kb, Vtb, cosp, sinp);

  hipLaunchKernelGGL(attn_kernel, dim3(16, NB * 16), dim3(512), 0, stream,
                     Qb, Kb, Vtb, attnb);

  hipLaunchKernelGGL(gemm_out, dim3(DM / 64, MTOT / 128), dim3(256), 0, stream,
                     attnb, wob, (float*)d_out);
}